// Round 2
// baseline (514.879 us; speedup 1.0000x reference)
//
#include <hip/hip_runtime.h>
#include <hip/hip_bf16.h>
#include <cstdint>
#include <cstddef>

// SelfAttention: B=8, S=2048, D_in=D_att=512, fp32 in/out.
// Pipeline: [proj GEMM fp16-MFMA] -> per-2-batch-chunk { [scores GEMM] -> [softmax] -> [PV GEMM] }
// All MFMA inputs are fp16 (ulp 2^-11; bf16's 2^-8 failed absmax by 1.6x).
// ws layout: qh/kh/vh fp16 (3*16MB) | S fp32 (2*2048*2048*4 = 32MB) | P fp16 (16MB) => 96MB.

#define SEQ 2048
#define DIM 512
#define NB 8
#define BSZ (NB * SEQ) /* 16384 rows of x */
#define CHUNK 2

typedef __attribute__((ext_vector_type(8))) _Float16 half8;  // 8 fp16 = 4 VGPRs
typedef __attribute__((ext_vector_type(4))) float f32x4;     // MFMA accumulator

__device__ __forceinline__ unsigned short f2h(float f) {
  _Float16 h = (_Float16)f;  // v_cvt_f16_f32, RNE
  return __builtin_bit_cast(unsigned short, h);
}

__device__ __forceinline__ half8 ld_frag(const unsigned short* p) {
  return *(const half8*)(const void*)p;
}

// ---------------------------------------------------------------------------
// Kernel 1: fused QKV projection. out[z] = fp16(X @ W[z] + b[z]), z in {0,1,2}.
// Tile 128x128, BK=32. LDS strides padded to 40 shorts (2-way bank alias = free).
// ---------------------------------------------------------------------------
__global__ __launch_bounds__(256) void proj_kernel(
    const float* __restrict__ X,
    const float* __restrict__ Wq, const float* __restrict__ bq,
    const float* __restrict__ Wk, const float* __restrict__ bk,
    const float* __restrict__ Wv, const float* __restrict__ bv,
    unsigned short* __restrict__ outbase)
{
  const int z = blockIdx.z;
  const float* W    = (z == 0) ? Wq : (z == 1) ? Wk : Wv;
  const float* bias = (z == 0) ? bq : (z == 1) ? bk : bv;
  unsigned short* out = outbase + (size_t)z * BSZ * DIM;

  const int m0 = blockIdx.x * 128;
  const int n0 = blockIdx.y * 128;
  const int t    = threadIdx.x;
  const int lane = t & 63;
  const int wave = t >> 6;
  const int wrow = (wave >> 1) * 64;
  const int wcol = (wave & 1) * 64;
  const int lr = lane & 15;
  const int lq = (lane >> 4) * 8;

  __shared__ unsigned short As[128 * 40];  // X tile, fp16, [m][k]
  __shared__ unsigned short Bs[128 * 40];  // W^T tile, fp16, [n][k]

  f32x4 acc[4][4];
  const f32x4 zero = {0.f, 0.f, 0.f, 0.f};
#pragma unroll
  for (int r = 0; r < 4; r++)
#pragma unroll
    for (int c = 0; c < 4; c++) acc[r][c] = zero;

  for (int k0 = 0; k0 < DIM; k0 += 32) {
    __syncthreads();
    // stage X (fp32 -> fp16): 128 rows x 32 k = 1024 float4s, 4 per thread
#pragma unroll
    for (int i = 0; i < 4; i++) {
      int f = t + 256 * i;
      int row = f >> 3;
      int c4 = (f & 7) * 4;
      float4 v = *(const float4*)&X[(size_t)(m0 + row) * DIM + k0 + c4];
      unsigned short* d = &As[row * 40 + c4];
      d[0] = f2h(v.x); d[1] = f2h(v.y); d[2] = f2h(v.z); d[3] = f2h(v.w);
    }
    // stage W^T: Bs[n][k] = W[k0+k][n0+n]
#pragma unroll
    for (int i = 0; i < 4; i++) {
      int f = t + 256 * i;
      int kr = f & 31;
      int n4 = (f >> 5) * 4;
      float4 v = *(const float4*)&W[(size_t)(k0 + kr) * DIM + n0 + n4];
      Bs[(n4 + 0) * 40 + kr] = f2h(v.x);
      Bs[(n4 + 1) * 40 + kr] = f2h(v.y);
      Bs[(n4 + 2) * 40 + kr] = f2h(v.z);
      Bs[(n4 + 3) * 40 + kr] = f2h(v.w);
    }
    __syncthreads();

    half8 a[4], b[4];
#pragma unroll
    for (int r = 0; r < 4; r++) a[r] = ld_frag(&As[(wrow + 16 * r + lr) * 40 + lq]);
#pragma unroll
    for (int c = 0; c < 4; c++) b[c] = ld_frag(&Bs[(wcol + 16 * c + lr) * 40 + lq]);
#pragma unroll
    for (int r = 0; r < 4; r++)
#pragma unroll
      for (int c = 0; c < 4; c++)
        acc[r][c] = __builtin_amdgcn_mfma_f32_16x16x32_f16(a[r], b[c], acc[r][c], 0, 0, 0);
  }

  // epilogue: +bias, cast fp16. C layout: col=lane&15, row=(lane>>4)*4+e.
#pragma unroll
  for (int c = 0; c < 4; c++) {
    int col = n0 + wcol + 16 * c + lr;
    float bb = bias[col];
#pragma unroll
    for (int r = 0; r < 4; r++) {
#pragma unroll
      for (int e = 0; e < 4; e++) {
        int row = m0 + wrow + 16 * r + (lane >> 4) * 4 + e;
        out[(size_t)row * DIM + col] = f2h(acc[r][c][e] + bb);
      }
    }
  }
}

// ---------------------------------------------------------------------------
// Kernel 2: scores S = Q @ K^T (fp32 out). Both operands row-major fp16 [row][512].
// Tile 128x128, BK=64.
// ---------------------------------------------------------------------------
__global__ __launch_bounds__(256) void scores_kernel(
    const unsigned short* __restrict__ Qb,
    const unsigned short* __restrict__ Kb,
    float* __restrict__ Sc)
{
  const int zb = blockIdx.z;
  const unsigned short* Q = Qb + (size_t)zb * SEQ * DIM;
  const unsigned short* K = Kb + (size_t)zb * SEQ * DIM;
  float* S = Sc + (size_t)zb * SEQ * SEQ;

  const int n0 = blockIdx.x * 128;
  const int m0 = blockIdx.y * 128;
  const int t = threadIdx.x;
  const int lane = t & 63;
  const int wave = t >> 6;
  const int wrow = (wave >> 1) * 64;
  const int wcol = (wave & 1) * 64;
  const int lr = lane & 15;
  const int lq = (lane >> 4) * 8;

  __shared__ unsigned short As[128 * 72];
  __shared__ unsigned short Bs[128 * 72];

  f32x4 acc[4][4];
  const f32x4 zero = {0.f, 0.f, 0.f, 0.f};
#pragma unroll
  for (int r = 0; r < 4; r++)
#pragma unroll
    for (int c = 0; c < 4; c++) acc[r][c] = zero;

  for (int k0 = 0; k0 < DIM; k0 += 64) {
    __syncthreads();
    // 1024 16B-chunks per matrix, 4 per thread
#pragma unroll
    for (int i = 0; i < 4; i++) {
      int f = t + 256 * i;
      int row = f >> 3;
      int c8 = (f & 7) * 8;
      *(uint4*)&As[row * 72 + c8] = *(const uint4*)&Q[(size_t)(m0 + row) * DIM + k0 + c8];
      *(uint4*)&Bs[row * 72 + c8] = *(const uint4*)&K[(size_t)(n0 + row) * DIM + k0 + c8];
    }
    __syncthreads();
#pragma unroll
    for (int kk = 0; kk < 64; kk += 32) {
      half8 a[4], b[4];
#pragma unroll
      for (int r = 0; r < 4; r++) a[r] = ld_frag(&As[(wrow + 16 * r + lr) * 72 + kk + lq]);
#pragma unroll
      for (int c = 0; c < 4; c++) b[c] = ld_frag(&Bs[(wcol + 16 * c + lr) * 72 + kk + lq]);
#pragma unroll
      for (int r = 0; r < 4; r++)
#pragma unroll
        for (int c = 0; c < 4; c++)
          acc[r][c] = __builtin_amdgcn_mfma_f32_16x16x32_f16(a[r], b[c], acc[r][c], 0, 0, 0);
    }
  }
#pragma unroll
  for (int r = 0; r < 4; r++)
#pragma unroll
    for (int c = 0; c < 4; c++)
#pragma unroll
      for (int e = 0; e < 4; e++) {
        int row = m0 + wrow + 16 * r + (lane >> 4) * 4 + e;
        int col = n0 + wcol + 16 * c + lr;
        S[(size_t)row * SEQ + col] = acc[r][c][e];
      }
}

// ---------------------------------------------------------------------------
// Kernel 3: row softmax. One 256-thread block per row of 2048 fp32 scores.
// Writes normalized probabilities as fp16.
// ---------------------------------------------------------------------------
__global__ __launch_bounds__(256) void softmax_kernel(
    const float* __restrict__ Sc, unsigned short* __restrict__ P)
{
  const size_t r = blockIdx.x;
  const float* s = Sc + r * SEQ;
  unsigned short* p = P + r * SEQ;
  const int t = threadIdx.x;
  const int lane = t & 63;
  const int w = t >> 6;

  float4 v0 = ((const float4*)s)[t];
  float4 v1 = ((const float4*)s)[t + 256];

  float m = fmaxf(fmaxf(fmaxf(v0.x, v0.y), fmaxf(v0.z, v0.w)),
                  fmaxf(fmaxf(v1.x, v1.y), fmaxf(v1.z, v1.w)));
  for (int off = 1; off < 64; off <<= 1) m = fmaxf(m, __shfl_xor(m, off, 64));

  __shared__ float red[4];
  if (lane == 0) red[w] = m;
  __syncthreads();
  m = fmaxf(fmaxf(red[0], red[1]), fmaxf(red[2], red[3]));
  __syncthreads();

  const float L2E = 1.4426950408889634f;
  float e0 = exp2f((v0.x - m) * L2E);
  float e1 = exp2f((v0.y - m) * L2E);
  float e2 = exp2f((v0.z - m) * L2E);
  float e3 = exp2f((v0.w - m) * L2E);
  float e4 = exp2f((v1.x - m) * L2E);
  float e5 = exp2f((v1.y - m) * L2E);
  float e6 = exp2f((v1.z - m) * L2E);
  float e7 = exp2f((v1.w - m) * L2E);
  float sum = ((e0 + e1) + (e2 + e3)) + ((e4 + e5) + (e6 + e7));
  for (int off = 1; off < 64; off <<= 1) sum += __shfl_xor(sum, off, 64);
  if (lane == 0) red[w] = sum;
  __syncthreads();
  sum = (red[0] + red[1]) + (red[2] + red[3]);
  float inv = 1.0f / sum;

  ushort4 o0, o1;
  o0.x = f2h(e0 * inv); o0.y = f2h(e1 * inv); o0.z = f2h(e2 * inv); o0.w = f2h(e3 * inv);
  o1.x = f2h(e4 * inv); o1.y = f2h(e5 * inv); o1.z = f2h(e6 * inv); o1.w = f2h(e7 * inv);
  *(ushort4*)&p[4 * t] = o0;
  *(ushort4*)&p[1024 + 4 * t] = o1;
}

// ---------------------------------------------------------------------------
// Kernel 4: O = P @ V (fp32 out to d_out). Tile M=64, N=128, BK=64.
// V staged transposed in LDS (Bt[n][k]) so b-frags are contiguous ds_read_b128.
// ---------------------------------------------------------------------------
__global__ __launch_bounds__(256) void pv_kernel(
    const unsigned short* __restrict__ Pb,
    const unsigned short* __restrict__ Vb,
    float* __restrict__ Ob)
{
  const int zb = blockIdx.z;
  const unsigned short* P = Pb + (size_t)zb * SEQ * SEQ;
  const unsigned short* V = Vb + (size_t)zb * SEQ * DIM;
  float* O = Ob + (size_t)zb * SEQ * DIM;

  const int n0 = blockIdx.x * 128;
  const int m0 = blockIdx.y * 64;
  const int t = threadIdx.x;
  const int lane = t & 63;
  const int wave = t >> 6;
  const int wrow = (wave >> 1) * 32;
  const int wcol = (wave & 1) * 64;
  const int lr = lane & 15;
  const int lq = (lane >> 4) * 8;

  __shared__ unsigned short As[64 * 72];   // P tile [m][k]
  __shared__ unsigned short Bs[128 * 72];  // V^T tile [n][k]

  f32x4 acc[2][4];
  const f32x4 zero = {0.f, 0.f, 0.f, 0.f};
#pragma unroll
  for (int r = 0; r < 2; r++)
#pragma unroll
    for (int c = 0; c < 4; c++) acc[r][c] = zero;

  for (int k0 = 0; k0 < SEQ; k0 += 64) {
    __syncthreads();
    // A: 64x64 shorts = 512 chunks, 2 per thread
#pragma unroll
    for (int i = 0; i < 2; i++) {
      int f = t + 256 * i;
      int row = f >> 3;
      int c8 = (f & 7) * 8;
      *(uint4*)&As[row * 72 + c8] = *(const uint4*)&P[(size_t)(m0 + row) * SEQ + k0 + c8];
    }
    // B: transpose-stage V tile [k0..+63][n0..+127] -> Bs[n][k]
#pragma unroll
    for (int i = 0; i < 4; i++) {
      int f = t + 256 * i;
      int kr = f & 63;
      int n8 = (f >> 6) * 8;
      uint4 raw = *(const uint4*)&V[(size_t)(k0 + kr) * DIM + n0 + n8];
      unsigned short tmp[8];
      *(uint4*)tmp = raw;
#pragma unroll
      for (int j = 0; j < 8; j++) Bs[(n8 + j) * 72 + kr] = tmp[j];
    }
    __syncthreads();
#pragma unroll
    for (int kk = 0; kk < 64; kk += 32) {
      half8 a[2], b[4];
#pragma unroll
      for (int r = 0; r < 2; r++) a[r] = ld_frag(&As[(wrow + 16 * r + lr) * 72 + kk + lq]);
#pragma unroll
      for (int c = 0; c < 4; c++) b[c] = ld_frag(&Bs[(wcol + 16 * c + lr) * 72 + kk + lq]);
#pragma unroll
      for (int r = 0; r < 2; r++)
#pragma unroll
        for (int c = 0; c < 4; c++)
          acc[r][c] = __builtin_amdgcn_mfma_f32_16x16x32_f16(a[r], b[c], acc[r][c], 0, 0, 0);
    }
  }
#pragma unroll
  for (int r = 0; r < 2; r++)
#pragma unroll
    for (int c = 0; c < 4; c++)
#pragma unroll
      for (int e = 0; e < 4; e++) {
        int row = m0 + wrow + 16 * r + (lane >> 4) * 4 + e;
        int col = n0 + wcol + 16 * c + lr;
        O[(size_t)row * DIM + col] = acc[r][c][e];
      }
}

// ---------------------------------------------------------------------------
extern "C" void kernel_launch(void* const* d_in, const int* in_sizes, int n_in,
                              void* d_out, int out_size, void* d_ws, size_t ws_size,
                              hipStream_t stream)
{
  const float* X  = (const float*)d_in[0];
  const float* Wq = (const float*)d_in[1];
  const float* bq = (const float*)d_in[2];
  const float* Wk = (const float*)d_in[3];
  const float* bk = (const float*)d_in[4];
  const float* Wv = (const float*)d_in[5];
  const float* bv = (const float*)d_in[6];
  float* Out = (float*)d_out;

  char* ws = (char*)d_ws;
  unsigned short* qh = (unsigned short*)ws;
  unsigned short* kh = qh + (size_t)BSZ * DIM;
  unsigned short* vh = qh + 2 * (size_t)BSZ * DIM;
  size_t qkv_bytes = 3 * (size_t)BSZ * DIM * 2;                 // 48 MB
  float* Sb = (float*)(ws + qkv_bytes);                          // 32 MB (CHUNK batches)
  unsigned short* Pb = (unsigned short*)(ws + qkv_bytes + (size_t)CHUNK * SEQ * SEQ * 4);  // 16 MB

  // 1) QKV projection (all three weights in one launch via grid.z)
  proj_kernel<<<dim3(BSZ / 128, DIM / 128, 3), 256, 0, stream>>>(
      X, Wq, bq, Wk, bk, Wv, bv, qh);

  // 2) per-chunk: scores -> softmax -> PV
  for (int b0 = 0; b0 < NB; b0 += CHUNK) {
    scores_kernel<<<dim3(SEQ / 128, SEQ / 128, CHUNK), 256, 0, stream>>>(
        qh + (size_t)b0 * SEQ * DIM, kh + (size_t)b0 * SEQ * DIM, Sb);
    softmax_kernel<<<dim3(CHUNK * SEQ), 256, 0, stream>>>(Sb, Pb);
    pv_kernel<<<dim3(DIM / 128, SEQ / 64, CHUNK), 256, 0, stream>>>(
        Pb, vh + (size_t)b0 * SEQ * DIM, Out + (size_t)b0 * SEQ * DIM);
  }
}

// Round 3
// 390.402 us; speedup vs baseline: 1.3188x; 1.3188x over previous
//
#include <hip/hip_runtime.h>
#include <cstdint>
#include <cstddef>

// SelfAttention: B=8, S=2048, D=512, fp32 in/out.
// R3: all GEMMs pure fp16 + global_load_lds(16B) staging (m97 structure).
// cvt_x/cvt_w pre-convert inputs; vtrans pre-transposes V; S/P fp16 in-place.
// ws: [qh 16M][kh 16M][vh 16M][vt 16M][SP 16M (aliases xh)][Wt 1.5M] = 81.5 MiB.

#define SEQ 2048
#define DIM 512
#define NB 8
#define BSZ (NB * SEQ)
#define CHUNK 2

typedef __attribute__((ext_vector_type(8))) _Float16 half8;
typedef __attribute__((ext_vector_type(4))) float f32x4;

__device__ __forceinline__ unsigned short f2h(float f) {
  _Float16 h = (_Float16)f;
  return __builtin_bit_cast(unsigned short, h);
}
__device__ __forceinline__ float h2f(unsigned short u) {
  return (float)__builtin_bit_cast(_Float16, u);
}
__device__ __forceinline__ half8 ld_frag(const unsigned short* p) {
  return *(const half8*)(const void*)p;
}
// async global->LDS, 16B per lane. lds dest = wave-uniform base + lane*16.
__device__ __forceinline__ void gl_lds16(const unsigned short* g, unsigned short* l) {
  __builtin_amdgcn_global_load_lds(
      (__attribute__((address_space(1))) void*)g,
      (__attribute__((address_space(3))) void*)l, 16, 0, 0);
}

// ---------------------------------------------------------------------------
// cvt_x: X fp32 -> xh fp16. 8 elems/thread.
// ---------------------------------------------------------------------------
__global__ __launch_bounds__(256) void cvt_x_kernel(
    const float* __restrict__ X, unsigned short* __restrict__ xh)
{
  size_t i0 = ((size_t)blockIdx.x * 256 + threadIdx.x) * 8;
  float4 a = *(const float4*)&X[i0];
  float4 b = *(const float4*)&X[i0 + 4];
  ushort4 o0; o0.x = f2h(a.x); o0.y = f2h(a.y); o0.z = f2h(a.z); o0.w = f2h(a.w);
  ushort4 o1; o1.x = f2h(b.x); o1.y = f2h(b.y); o1.z = f2h(b.z); o1.w = f2h(b.w);
  *(ushort4*)&xh[i0] = o0;
  *(ushort4*)&xh[i0 + 4] = o1;
}

// ---------------------------------------------------------------------------
// cvt_w: W[z] fp32 [k][n] -> Wt[z] fp16 [n][k] (64x64 LDS-tiled transpose).
// ---------------------------------------------------------------------------
__global__ __launch_bounds__(256) void cvt_w_kernel(
    const float* __restrict__ Wq, const float* __restrict__ Wk,
    const float* __restrict__ Wv, unsigned short* __restrict__ Wt)
{
  const int z = blockIdx.z;
  const float* W = (z == 0) ? Wq : (z == 1) ? Wk : Wv;
  unsigned short* out = Wt + (size_t)z * DIM * DIM;
  const int k0 = blockIdx.x * 64, n0 = blockIdx.y * 64;
  const int t = threadIdx.x;
  __shared__ unsigned short tl[64 * 72];
#pragma unroll
  for (int i = 0; i < 4; i++) {
    int f = t + 256 * i;
    int kr = f >> 4, c4 = (f & 15) * 4;
    float4 v = *(const float4*)&W[(size_t)(k0 + kr) * DIM + n0 + c4];
    tl[(c4 + 0) * 72 + kr] = f2h(v.x);
    tl[(c4 + 1) * 72 + kr] = f2h(v.y);
    tl[(c4 + 2) * 72 + kr] = f2h(v.z);
    tl[(c4 + 3) * 72 + kr] = f2h(v.w);
  }
  __syncthreads();
#pragma unroll
  for (int i = 0; i < 2; i++) {
    int f = t + 256 * i;
    int nr = f >> 3, k8 = (f & 7) * 8;
    *(uint4*)&out[(size_t)(n0 + nr) * DIM + k0 + k8] = *(const uint4*)&tl[nr * 72 + k8];
  }
}

// ---------------------------------------------------------------------------
// proj: qkv[z] = fp16(xh @ Wt[z]^T + b[z]). 128x128, BK=64, global_load_lds.
// ---------------------------------------------------------------------------
__global__ __launch_bounds__(256) void proj_kernel(
    const unsigned short* __restrict__ xh, const unsigned short* __restrict__ Wt,
    const float* __restrict__ bq, const float* __restrict__ bk,
    const float* __restrict__ bv, unsigned short* __restrict__ outbase)
{
  const int z = blockIdx.z;
  const unsigned short* Wz = Wt + (size_t)z * DIM * DIM;
  const float* bias = (z == 0) ? bq : (z == 1) ? bk : bv;
  unsigned short* out = outbase + (size_t)z * BSZ * DIM;
  const int m0 = blockIdx.x * 128, n0 = blockIdx.y * 128;
  const int t = threadIdx.x, lane = t & 63, wave = t >> 6;
  const int wrow = (wave >> 1) * 64, wcol = (wave & 1) * 64;
  const int lr = lane & 15, lq = (lane >> 4) * 8;

  __shared__ unsigned short As[128 * 64];
  __shared__ unsigned short Bs[128 * 64];

  f32x4 acc[4][4];
  const f32x4 zero = {0.f, 0.f, 0.f, 0.f};
#pragma unroll
  for (int r = 0; r < 4; r++)
#pragma unroll
    for (int c = 0; c < 4; c++) acc[r][c] = zero;

  for (int k0 = 0; k0 < DIM; k0 += 64) {
    __syncthreads();
#pragma unroll
    for (int i = 0; i < 4; i++) {
      int f = t + 256 * i;
      int row = f >> 3, c8 = (f & 7) * 8;
      gl_lds16(&xh[(size_t)(m0 + row) * DIM + k0 + c8], &As[i * 2048 + wave * 512]);
      gl_lds16(&Wz[(size_t)(n0 + row) * DIM + k0 + c8], &Bs[i * 2048 + wave * 512]);
    }
    __syncthreads();
#pragma unroll
    for (int kk = 0; kk < 64; kk += 32) {
      half8 a[4], b[4];
#pragma unroll
      for (int r = 0; r < 4; r++) a[r] = ld_frag(&As[(wrow + 16 * r + lr) * 64 + kk + lq]);
#pragma unroll
      for (int c = 0; c < 4; c++) b[c] = ld_frag(&Bs[(wcol + 16 * c + lr) * 64 + kk + lq]);
#pragma unroll
      for (int r = 0; r < 4; r++)
#pragma unroll
        for (int c = 0; c < 4; c++)
          acc[r][c] = __builtin_amdgcn_mfma_f32_16x16x32_f16(a[r], b[c], acc[r][c], 0, 0, 0);
    }
  }
#pragma unroll
  for (int c = 0; c < 4; c++) {
    int col = n0 + wcol + 16 * c + lr;
    float bb = bias[col];
#pragma unroll
    for (int r = 0; r < 4; r++)
#pragma unroll
      for (int e = 0; e < 4; e++) {
        int row = m0 + wrow + 16 * r + (lane >> 4) * 4 + e;
        out[(size_t)row * DIM + col] = f2h(acc[r][c][e] + bb);
      }
  }
}

// ---------------------------------------------------------------------------
// vtrans: vh [b*S+s][n] -> vt [b][n][s] (64x64 LDS-tiled).
// ---------------------------------------------------------------------------
__global__ __launch_bounds__(256) void vtrans_kernel(
    const unsigned short* __restrict__ vh, unsigned short* __restrict__ vt)
{
  const int b = blockIdx.z;
  const int s0 = blockIdx.x * 64, n0 = blockIdx.y * 64;
  const int t = threadIdx.x;
  __shared__ unsigned short tl[64 * 72];
#pragma unroll
  for (int i = 0; i < 2; i++) {
    int f = t + 256 * i;
    int sr = f >> 3, c8 = (f & 7) * 8;
    uint4 raw = *(const uint4*)&vh[((size_t)b * SEQ + s0 + sr) * DIM + n0 + c8];
    unsigned short u[8];
    *(uint4*)u = raw;
#pragma unroll
    for (int j = 0; j < 8; j++) tl[(c8 + j) * 72 + sr] = u[j];
  }
  __syncthreads();
#pragma unroll
  for (int i = 0; i < 2; i++) {
    int f = t + 256 * i;
    int nr = f >> 3, s8 = (f & 7) * 8;
    *(uint4*)&vt[((size_t)b * DIM + n0 + nr) * SEQ + s0 + s8] = *(const uint4*)&tl[nr * 72 + s8];
  }
}

// ---------------------------------------------------------------------------
// scores: S = fp16(Q @ K^T). 128x128, BK=64, global_load_lds.
// ---------------------------------------------------------------------------
__global__ __launch_bounds__(256) void scores_kernel(
    const unsigned short* __restrict__ Qb, const unsigned short* __restrict__ Kb,
    unsigned short* __restrict__ Sp)
{
  const int zb = blockIdx.z;
  const unsigned short* Q = Qb + (size_t)zb * SEQ * DIM;
  const unsigned short* K = Kb + (size_t)zb * SEQ * DIM;
  unsigned short* S = Sp + (size_t)zb * SEQ * SEQ;
  const int n0 = blockIdx.x * 128, m0 = blockIdx.y * 128;
  const int t = threadIdx.x, lane = t & 63, wave = t >> 6;
  const int wrow = (wave >> 1) * 64, wcol = (wave & 1) * 64;
  const int lr = lane & 15, lq = (lane >> 4) * 8;

  __shared__ unsigned short As[128 * 64];
  __shared__ unsigned short Bs[128 * 64];

  f32x4 acc[4][4];
  const f32x4 zero = {0.f, 0.f, 0.f, 0.f};
#pragma unroll
  for (int r = 0; r < 4; r++)
#pragma unroll
    for (int c = 0; c < 4; c++) acc[r][c] = zero;

  for (int k0 = 0; k0 < DIM; k0 += 64) {
    __syncthreads();
#pragma unroll
    for (int i = 0; i < 4; i++) {
      int f = t + 256 * i;
      int row = f >> 3, c8 = (f & 7) * 8;
      gl_lds16(&Q[(size_t)(m0 + row) * DIM + k0 + c8], &As[i * 2048 + wave * 512]);
      gl_lds16(&K[(size_t)(n0 + row) * DIM + k0 + c8], &Bs[i * 2048 + wave * 512]);
    }
    __syncthreads();
#pragma unroll
    for (int kk = 0; kk < 64; kk += 32) {
      half8 a[4], b[4];
#pragma unroll
      for (int r = 0; r < 4; r++) a[r] = ld_frag(&As[(wrow + 16 * r + lr) * 64 + kk + lq]);
#pragma unroll
      for (int c = 0; c < 4; c++) b[c] = ld_frag(&Bs[(wcol + 16 * c + lr) * 64 + kk + lq]);
#pragma unroll
      for (int r = 0; r < 4; r++)
#pragma unroll
        for (int c = 0; c < 4; c++)
          acc[r][c] = __builtin_amdgcn_mfma_f32_16x16x32_f16(a[r], b[c], acc[r][c], 0, 0, 0);
    }
  }
#pragma unroll
  for (int r = 0; r < 4; r++)
#pragma unroll
    for (int c = 0; c < 4; c++)
#pragma unroll
      for (int e = 0; e < 4; e++) {
        int row = m0 + wrow + 16 * r + (lane >> 4) * 4 + e;
        int col = n0 + wcol + 16 * c + lr;
        S[(size_t)row * SEQ + col] = f2h(acc[r][c][e]);
      }
}

// ---------------------------------------------------------------------------
// softmax: fp16 row in-place. One block per row; one uint4 (8 halfs)/thread.
// ---------------------------------------------------------------------------
__global__ __launch_bounds__(256) void softmax_kernel(unsigned short* __restrict__ Sp)
{
  unsigned short* row = Sp + (size_t)blockIdx.x * SEQ;
  const int t = threadIdx.x, lane = t & 63, w = t >> 6;

  uint4 raw = *(const uint4*)&row[t * 8];
  unsigned short u[8];
  *(uint4*)u = raw;
  float v[8];
#pragma unroll
  for (int j = 0; j < 8; j++) v[j] = h2f(u[j]);

  float m = v[0];
#pragma unroll
  for (int j = 1; j < 8; j++) m = fmaxf(m, v[j]);
  for (int off = 1; off < 64; off <<= 1) m = fmaxf(m, __shfl_xor(m, off, 64));

  __shared__ float red[4];
  if (lane == 0) red[w] = m;
  __syncthreads();
  m = fmaxf(fmaxf(red[0], red[1]), fmaxf(red[2], red[3]));
  __syncthreads();

  const float L2E = 1.4426950408889634f;
  float sum = 0.f;
#pragma unroll
  for (int j = 0; j < 8; j++) {
    v[j] = exp2f((v[j] - m) * L2E);
    sum += v[j];
  }
  for (int off = 1; off < 64; off <<= 1) sum += __shfl_xor(sum, off, 64);
  if (lane == 0) red[w] = sum;
  __syncthreads();
  sum = (red[0] + red[1]) + (red[2] + red[3]);
  float inv = 1.0f / sum;

#pragma unroll
  for (int j = 0; j < 8; j++) u[j] = f2h(v[j] * inv);
  *(uint4*)&row[t * 8] = *(const uint4*)u;
}

// ---------------------------------------------------------------------------
// pv: O = P @ Vt^T (fp32 out). Tile M=128, N=64, BK=64, global_load_lds.
// ---------------------------------------------------------------------------
__global__ __launch_bounds__(256) void pv_kernel(
    const unsigned short* __restrict__ Pp, const unsigned short* __restrict__ Vt,
    float* __restrict__ Ob)
{
  const int zb = blockIdx.z;
  const unsigned short* P = Pp + (size_t)zb * SEQ * SEQ;
  const unsigned short* V = Vt + (size_t)zb * DIM * SEQ;  // [n][s]
  float* O = Ob + (size_t)zb * SEQ * DIM;
  const int n0 = blockIdx.x * 64, m0 = blockIdx.y * 128;
  const int t = threadIdx.x, lane = t & 63, wave = t >> 6;
  const int wrow = wave * 32;
  const int lr = lane & 15, lq = (lane >> 4) * 8;

  __shared__ unsigned short As[128 * 64];
  __shared__ unsigned short Bs[64 * 64];

  f32x4 acc[2][4];
  const f32x4 zero = {0.f, 0.f, 0.f, 0.f};
#pragma unroll
  for (int r = 0; r < 2; r++)
#pragma unroll
    for (int c = 0; c < 4; c++) acc[r][c] = zero;

  for (int k0 = 0; k0 < SEQ; k0 += 64) {
    __syncthreads();
#pragma unroll
    for (int i = 0; i < 4; i++) {
      int f = t + 256 * i;
      int row = f >> 3, c8 = (f & 7) * 8;
      gl_lds16(&P[(size_t)(m0 + row) * SEQ + k0 + c8], &As[i * 2048 + wave * 512]);
    }
#pragma unroll
    for (int i = 0; i < 2; i++) {
      int f = t + 256 * i;
      int row = f >> 3, c8 = (f & 7) * 8;
      gl_lds16(&V[(size_t)(n0 + row) * SEQ + k0 + c8], &Bs[i * 2048 + wave * 512]);
    }
    __syncthreads();
#pragma unroll
    for (int kk = 0; kk < 64; kk += 32) {
      half8 a[2], b[4];
#pragma unroll
      for (int r = 0; r < 2; r++) a[r] = ld_frag(&As[(wrow + 16 * r + lr) * 64 + kk + lq]);
#pragma unroll
      for (int c = 0; c < 4; c++) b[c] = ld_frag(&Bs[(16 * c + lr) * 64 + kk + lq]);
#pragma unroll
      for (int r = 0; r < 2; r++)
#pragma unroll
        for (int c = 0; c < 4; c++)
          acc[r][c] = __builtin_amdgcn_mfma_f32_16x16x32_f16(a[r], b[c], acc[r][c], 0, 0, 0);
    }
  }
#pragma unroll
  for (int r = 0; r < 2; r++)
#pragma unroll
    for (int c = 0; c < 4; c++)
#pragma unroll
      for (int e = 0; e < 4; e++) {
        int row = m0 + wrow + 16 * r + (lane >> 4) * 4 + e;
        int col = n0 + 16 * c + lr;
        O[(size_t)row * DIM + col] = acc[r][c][e];
      }
}

// ---------------------------------------------------------------------------
extern "C" void kernel_launch(void* const* d_in, const int* in_sizes, int n_in,
                              void* d_out, int out_size, void* d_ws, size_t ws_size,
                              hipStream_t stream)
{
  const float* X  = (const float*)d_in[0];
  const float* Wq = (const float*)d_in[1];
  const float* bq = (const float*)d_in[2];
  const float* Wk = (const float*)d_in[3];
  const float* bk = (const float*)d_in[4];
  const float* Wv = (const float*)d_in[5];
  const float* bv = (const float*)d_in[6];
  float* Out = (float*)d_out;

  char* ws = (char*)d_ws;
  const size_t MB = 1u << 20;
  unsigned short* qh = (unsigned short*)(ws);            // 16 MiB
  unsigned short* kh = (unsigned short*)(ws + 16 * MB);  // 16 MiB
  unsigned short* vh = (unsigned short*)(ws + 32 * MB);  // 16 MiB (dead after vtrans)
  unsigned short* vt = (unsigned short*)(ws + 48 * MB);  // 16 MiB
  unsigned short* SP = (unsigned short*)(ws + 64 * MB);  // 16 MiB (S/P fp16 in-place)
  unsigned short* xh = (unsigned short*)(ws + 64 * MB);  // aliases SP; dead before scores
  unsigned short* Wt = (unsigned short*)(ws + 80 * MB);  // 1.5 MiB

  cvt_x_kernel<<<dim3(BSZ * DIM / 2048), 256, 0, stream>>>(X, xh);
  cvt_w_kernel<<<dim3(8, 8, 3), 256, 0, stream>>>(Wq, Wk, Wv, Wt);
  proj_kernel<<<dim3(BSZ / 128, DIM / 128, 3), 256, 0, stream>>>(
      xh, Wt, bq, bk, bv, qh);
  vtrans_kernel<<<dim3(SEQ / 64, DIM / 64, NB), 256, 0, stream>>>(vh, vt);

  for (int b0 = 0; b0 < NB; b0 += CHUNK) {
    scores_kernel<<<dim3(SEQ / 128, SEQ / 128, CHUNK), 256, 0, stream>>>(
        qh + (size_t)b0 * SEQ * DIM, kh + (size_t)b0 * SEQ * DIM, SP);
    softmax_kernel<<<dim3(CHUNK * SEQ), 256, 0, stream>>>(SP);
    pv_kernel<<<dim3(DIM / 64, SEQ / 128, CHUNK), 256, 0, stream>>>(
        SP, vt + (size_t)b0 * DIM * SEQ, Out + (size_t)b0 * SEQ * DIM);
  }
}